// Round 1
// baseline (25.726 us; speedup 1.0000x reference)
//
#include <hip/hip_runtime.h>

typedef int v4i __attribute__((ext_vector_type(4)));

// ---------------- absmax of x and w ----------------
__global__ __launch_bounds__(256) void absmax_kernel(
    const float* __restrict__ x, int nx4,
    const float* __restrict__ w, int nw4,
    unsigned int* __restrict__ res) {
  int tid = blockIdx.x * blockDim.x + threadIdx.x;
  int stride = gridDim.x * blockDim.x;
  float mx = 0.f, mw = 0.f;
  const float4* x4 = (const float4*)x;
  const float4* w4 = (const float4*)w;
  for (int i = tid; i < nx4; i += stride) {
    float4 v = x4[i];
    mx = fmaxf(mx, fmaxf(fmaxf(fabsf(v.x), fabsf(v.y)),
                         fmaxf(fabsf(v.z), fabsf(v.w))));
  }
  for (int i = tid; i < nw4; i += stride) {
    float4 v = w4[i];
    mw = fmaxf(mw, fmaxf(fmaxf(fabsf(v.x), fabsf(v.y)),
                         fmaxf(fabsf(v.z), fabsf(v.w))));
  }
  // wave64 butterfly reduce
  #pragma unroll
  for (int off = 32; off; off >>= 1) {
    mx = fmaxf(mx, __shfl_xor(mx, off));
    mw = fmaxf(mw, __shfl_xor(mw, off));
  }
  __shared__ float smx[4], smw[4];
  int wid = threadIdx.x >> 6;
  if ((threadIdx.x & 63) == 0) { smx[wid] = mx; smw[wid] = mw; }
  __syncthreads();
  if (threadIdx.x == 0) {
    float a = fmaxf(fmaxf(smx[0], smx[1]), fmaxf(smx[2], smx[3]));
    float b = fmaxf(fmaxf(smw[0], smw[1]), fmaxf(smw[2], smw[3]));
    atomicMax(&res[0], __float_as_uint(a));  // nonneg floats: uint order == float order
    atomicMax(&res[1], __float_as_uint(b));
  }
}

// ---------------- quantize x, w -> int8 ----------------
__device__ __forceinline__ int quant1(float v, float s) {
  float t = rintf(v / s);                       // round-half-even, matches jnp.round
  t = fminf(fmaxf(t, -128.f), 127.f);
  return (int)t;
}

__global__ __launch_bounds__(256) void quant_kernel(
    const float* __restrict__ x, int nx4,
    const float* __restrict__ w, int nw4,
    const unsigned int* __restrict__ amax,
    const float* __restrict__ Tf, const float* __restrict__ Tw,
    char* __restrict__ qx, char* __restrict__ qw) {
  float sx = (0.95f * Tf[0] + 0.05f * __uint_as_float(amax[0])) / 127.0f;
  float sw = (0.95f * Tw[0] + 0.05f * __uint_as_float(amax[1])) / 127.0f;
  int tid = blockIdx.x * blockDim.x + threadIdx.x;
  int stride = gridDim.x * blockDim.x;
  const float4* x4 = (const float4*)x;
  const float4* w4 = (const float4*)w;
  int* qxi = (int*)qx;
  int* qwi = (int*)qw;
  for (int i = tid; i < nx4; i += stride) {
    float4 v = x4[i];
    int q0 = quant1(v.x, sx), q1 = quant1(v.y, sx);
    int q2 = quant1(v.z, sx), q3 = quant1(v.w, sx);
    qxi[i] = (q0 & 255) | ((q1 & 255) << 8) | ((q2 & 255) << 16) | (q3 << 24);
  }
  for (int i = tid; i < nw4; i += stride) {
    float4 v = w4[i];
    int q0 = quant1(v.x, sw), q1 = quant1(v.y, sw);
    int q2 = quant1(v.z, sw), q3 = quant1(v.w, sw);
    qwi[i] = (q0 & 255) | ((q1 & 255) << 8) | ((q2 & 255) << 16) | (q3 << 24);
  }
}

// ---------------- int8 MFMA GEMM + epilogue ----------------
// C[t,n] = sum_k qx[t,k]*qw[n,k];  out = C * (sx*sw) + bias[n]
// M=128, N=1024, K=1024.  One wave -> one 16x16 output tile. 512 waves.
__global__ __launch_bounds__(256) void gemm_kernel(
    const char* __restrict__ qx, const char* __restrict__ qw,
    const unsigned int* __restrict__ amax,
    const float* __restrict__ Tf, const float* __restrict__ Tw,
    const float* __restrict__ bias, float* __restrict__ out) {
  float sx = (0.95f * Tf[0] + 0.05f * __uint_as_float(amax[0])) / 127.0f;
  float sw = (0.95f * Tw[0] + 0.05f * __uint_as_float(amax[1])) / 127.0f;
  float s = sx * sw;

  int wave = (blockIdx.x << 2) | (threadIdx.x >> 6);  // 0..511
  int lane = threadIdx.x & 63;
  int mt = wave >> 6;   // 0..7   (M/16)
  int nt = wave & 63;   // 0..63  (N/16)

  int row = (mt << 4) + (lane & 15);
  int col = (nt << 4) + (lane & 15);
  int klo = (lane >> 4) << 4;  // 0,16,32,48 — 16 consecutive i8 per lane

  const v4i* arow = (const v4i*)(qx + row * 1024 + klo);  // +64B per K-step => +4 v4i
  const v4i* brow = (const v4i*)(qw + col * 1024 + klo);

  v4i acc = {0, 0, 0, 0};
  #pragma unroll
  for (int kk = 0; kk < 16; ++kk) {
    v4i a = arow[kk * 4];
    v4i b = brow[kk * 4];
    acc = __builtin_amdgcn_mfma_i32_16x16x64_i8(a, b, acc, 0, 0, 0);
  }

  // C/D layout: col = lane&15, row = (lane>>4)*4 + r
  int orow = (mt << 4) + ((lane >> 4) << 2);
  float bcol = bias[col];
  #pragma unroll
  for (int r = 0; r < 4; ++r) {
    out[(orow + r) * 1024 + col] = (float)acc[r] * s + bcol;
  }
}

extern "C" void kernel_launch(void* const* d_in, const int* in_sizes, int n_in,
                              void* d_out, int out_size, void* d_ws, size_t ws_size,
                              hipStream_t stream) {
  const float* x    = (const float*)d_in[0];   // [128,1024]
  const float* w    = (const float*)d_in[1];   // [1024,1024]
  const float* bias = (const float*)d_in[2];   // [1024]
  // d_in[3] = lut (unused: lut[a+128][b+128] == a*b exactly)
  const float* Tf   = (const float*)d_in[4];
  const float* Tw   = (const float*)d_in[5];
  float* out = (float*)d_out;

  unsigned int* amax = (unsigned int*)d_ws;
  char* qx = (char*)d_ws + 256;            // 128*1024 int8
  char* qw = qx + 128 * 1024;              // 1024*1024 int8

  hipMemsetAsync(d_ws, 0, 8, stream);      // zero absmax slots (uint-as-float 0.0)
  absmax_kernel<<<256, 256, 0, stream>>>(x, 131072 / 4, w, 1048576 / 4, amax);
  quant_kernel<<<512, 256, 0, stream>>>(x, 131072 / 4, w, 1048576 / 4,
                                        amax, Tf, Tw, qx, qw);
  gemm_kernel<<<128, 256, 0, stream>>>(qx, qw, amax, Tf, Tw, bias, out);
}

// Round 2
// 25.292 us; speedup vs baseline: 1.0172x; 1.0172x over previous
//
#include <hip/hip_runtime.h>

typedef int v4i __attribute__((ext_vector_type(4)));

// ---------------- kernel 1: per-block absmax partials (no atomics, no memset) ----------------
__global__ __launch_bounds__(256) void absmax_partial(
    const float* __restrict__ x, int nx4,
    const float* __restrict__ w, int nw4,
    float* __restrict__ partials) {
  int tid = blockIdx.x * 256 + threadIdx.x;
  int stride = gridDim.x * 256;
  float mx = 0.f, mw = 0.f;
  const float4* x4 = (const float4*)x;
  const float4* w4 = (const float4*)w;
  for (int i = tid; i < nx4; i += stride) {
    float4 v = x4[i];
    mx = fmaxf(mx, fmaxf(fmaxf(fabsf(v.x), fabsf(v.y)),
                         fmaxf(fabsf(v.z), fabsf(v.w))));
  }
  for (int i = tid; i < nw4; i += stride) {
    float4 v = w4[i];
    mw = fmaxf(mw, fmaxf(fmaxf(fabsf(v.x), fabsf(v.y)),
                         fmaxf(fabsf(v.z), fabsf(v.w))));
  }
  #pragma unroll
  for (int off = 32; off; off >>= 1) {
    mx = fmaxf(mx, __shfl_xor(mx, off));
    mw = fmaxf(mw, __shfl_xor(mw, off));
  }
  __shared__ float smx[4], smw[4];
  int wid = threadIdx.x >> 6;
  if ((threadIdx.x & 63) == 0) { smx[wid] = mx; smw[wid] = mw; }
  __syncthreads();
  if (threadIdx.x == 0) {
    partials[2 * blockIdx.x]     = fmaxf(fmaxf(smx[0], smx[1]), fmaxf(smx[2], smx[3]));
    partials[2 * blockIdx.x + 1] = fmaxf(fmaxf(smw[0], smw[1]), fmaxf(smw[2], smw[3]));
  }
}

// ---------------- kernel 2: fused reduce + quantize + int8 MFMA GEMM + epilogue ----------------
__device__ __forceinline__ int packq(float4 v, float inv) {
  float t0 = fminf(fmaxf(rintf(v.x * inv), -128.f), 127.f);
  float t1 = fminf(fmaxf(rintf(v.y * inv), -128.f), 127.f);
  float t2 = fminf(fmaxf(rintf(v.z * inv), -128.f), 127.f);
  float t3 = fminf(fmaxf(rintf(v.w * inv), -128.f), 127.f);
  int q0 = (int)t0, q1 = (int)t1, q2 = (int)t2, q3 = (int)t3;
  return (q0 & 255) | ((q1 & 255) << 8) | ((q2 & 255) << 16) | (q3 << 24);
}

__global__ __launch_bounds__(256) void fused_gemm(
    const float* __restrict__ x, const float* __restrict__ w,
    const float* __restrict__ partials,
    const float* __restrict__ Tf, const float* __restrict__ Tw,
    const float* __restrict__ bias, float* __restrict__ out) {
  int lane = threadIdx.x & 63;
  // reduce the 64 per-block partials across the wave (all lanes end with the max)
  float pm = partials[2 * lane];
  float pw = partials[2 * lane + 1];
  #pragma unroll
  for (int off = 32; off; off >>= 1) {
    pm = fmaxf(pm, __shfl_xor(pm, off));
    pw = fmaxf(pw, __shfl_xor(pw, off));
  }
  float TfN = 0.95f * Tf[0] + 0.05f * pm;
  float TwN = 0.95f * Tw[0] + 0.05f * pw;
  float sx = TfN * (1.0f / 127.0f);
  float sw = TwN * (1.0f / 127.0f);
  float inv_sx = 127.0f / TfN;
  float inv_sw = 127.0f / TwN;

  int wave = (blockIdx.x << 2) | (threadIdx.x >> 6);  // 0..511
  int mt = wave >> 6;   // 0..7
  int nt = wave & 63;   // 0..63
  int arow = (mt << 4) + (lane & 15);
  int brow = (nt << 4) + (lane & 15);
  int klo4 = (lane >> 4) << 2;  // float4 index of this lane's 16-k slice

  const float4* a4 = (const float4*)(x + arow * 1024) + klo4;
  const float4* b4 = (const float4*)(w + brow * 1024) + klo4;

  v4i acc = {0, 0, 0, 0};
  #pragma unroll
  for (int kk = 0; kk < 16; ++kk) {
    v4i a, b;
    a.x = packq(a4[kk * 16 + 0], inv_sx);
    a.y = packq(a4[kk * 16 + 1], inv_sx);
    a.z = packq(a4[kk * 16 + 2], inv_sx);
    a.w = packq(a4[kk * 16 + 3], inv_sx);
    b.x = packq(b4[kk * 16 + 0], inv_sw);
    b.y = packq(b4[kk * 16 + 1], inv_sw);
    b.z = packq(b4[kk * 16 + 2], inv_sw);
    b.w = packq(b4[kk * 16 + 3], inv_sw);
    acc = __builtin_amdgcn_mfma_i32_16x16x64_i8(a, b, acc, 0, 0, 0);
  }

  int orow = (mt << 4) + ((lane >> 4) << 2);
  int col  = (nt << 4) + (lane & 15);
  float bcol = bias[col];
  float s = sx * sw;
  #pragma unroll
  for (int r = 0; r < 4; ++r) {
    out[(orow + r) * 1024 + col] = (float)acc[r] * s + bcol;
  }
}

extern "C" void kernel_launch(void* const* d_in, const int* in_sizes, int n_in,
                              void* d_out, int out_size, void* d_ws, size_t ws_size,
                              hipStream_t stream) {
  const float* x    = (const float*)d_in[0];   // [128,1024]
  const float* w    = (const float*)d_in[1];   // [1024,1024]
  const float* bias = (const float*)d_in[2];   // [1024]
  // d_in[3] = lut (unused: lut[a+128][b+128] == a*b exactly)
  const float* Tf   = (const float*)d_in[4];
  const float* Tw   = (const float*)d_in[5];
  float* out = (float*)d_out;

  float* partials = (float*)d_ws;  // 64 blocks * 2 floats, written unconditionally

  absmax_partial<<<64, 256, 0, stream>>>(x, 131072 / 4, w, 1048576 / 4, partials);
  fused_gemm<<<128, 256, 0, stream>>>(x, w, partials, Tf, Tw, bias, out);
}